// Round 11
// baseline (376.334 us; speedup 1.0000x reference)
//
#include <hip/hip_runtime.h>
#include <hip/hip_bf16.h>

typedef __attribute__((ext_vector_type(8))) short bf16x8;
typedef __attribute__((ext_vector_type(4))) float f32x4;

__device__ inline ushort f2bf(float f) {
    uint u = __float_as_uint(f);
    u += 0x7fff + ((u >> 16) & 1);
    return (ushort)(u >> 16);
}
__device__ inline float bf2f(ushort h) {
    return __uint_as_float(((uint)h) << 16);
}

__device__ inline void gload16(const void* g, void* lds) {
    __builtin_amdgcn_global_load_lds(
        (const __attribute__((address_space(1))) void*)g,
        (__attribute__((address_space(3))) void*)lds, 16, 0, 0);
}

// ---------------- merged prep: src->bf16, 6 weight transpose-converts, bias concat ----------------
__global__ __launch_bounds__(256) void prep(
    const float* __restrict__ src, ushort* __restrict__ src16,
    const float* __restrict__ Wq, const float* __restrict__ Wk,
    const float* __restrict__ Wv, const float* __restrict__ Wo,
    const float* __restrict__ W1, const float* __restrict__ W2,
    ushort* __restrict__ wqkv, ushort* __restrict__ wot,
    ushort* __restrict__ w1t, ushort* __restrict__ w2t,
    const float* __restrict__ bq, const float* __restrict__ bk,
    const float* __restrict__ bv, float* __restrict__ bqkv) {
    __shared__ float tile[32][33];
    int bid = blockIdx.x;
    const int t = threadIdx.x;
    if (bid < 16384) {
        int i = bid * 256 + t;
        float4 a = ((const float4*)src)[i];
        ushort4 o;
        o.x = f2bf(a.x); o.y = f2bf(a.y); o.z = f2bf(a.z); o.w = f2bf(a.w);
        ((ushort4*)src16)[i] = o;
        return;
    }
    bid -= 16384;
    const float* in; ushort* out; int Kd, Nd;
    if (bid < 1024) {
        int m = bid >> 8;
        in = (m == 0) ? Wq : (m == 1) ? Wk : (m == 2) ? Wv : Wo;
        out = (m == 3) ? wot : (wqkv + m * 512 * 512);
        Kd = 512; Nd = 512; bid &= 255;
    } else if (bid < 2048) { in = W1; out = w1t; Kd = 512; Nd = 2048; bid -= 1024; }
    else if (bid < 3072) { in = W2; out = w2t; Kd = 2048; Nd = 512; bid -= 2048; }
    else {
        int i = (bid - 3072) * 256 + t;
        if (i < 512) bqkv[i] = bq[i];
        else if (i < 1024) bqkv[i] = bk[i - 512];
        else if (i < 1536) bqkv[i] = bv[i - 1024];
        return;
    }
    const int nx = Nd / 32;
    const int nbase = (bid % nx) * 32, kb = (bid / nx) * 32;
    const int tx = t & 31, ty = t >> 5;
#pragma unroll
    for (int i = 0; i < 4; i++)
        tile[ty + i * 8][tx] = in[(size_t)(kb + ty + i * 8) * Nd + nbase + tx];
    __syncthreads();
#pragma unroll
    for (int i = 0; i < 4; i++) {
        int n = nbase + ty + i * 8, k = kb + tx;
        out[(size_t)n * Kd + k] = f2bf(tile[tx][ty + i * 8]);
    }
}

// ============ 256x256 persistent GEMM -- faithful m201 8-phase port (BK=64) ============
// (512,2), 8 waves 2Mx4N, BK=64, 2 x 64KB dbuf, 4 phases per K-tile:
//   phase p: [4-12 ds_read_b128 (this phase's frags)] [2 gload16 stage units for
//   NEXT buffer] [lgkm(8)@p0 | vmcnt(4)@p1 | vmcnt(2)@p3] [BARRIER] [lgkm(0)]
//   [setprio1; 16 MFMA (m=2p,2p+1 x n x kk); setprio0] [BARRIER]
// Stage units (64 rows = 8KB each) ordered by NEXT-tile consumption:
//   p0:{B0,B1} p1:{B2,B3} p2:{A0,A2} p3:{A1,A3}
//   (phase 0 reads ALL B + A-rows 0-31 (units A0/A2); phases 2-3 read A1/A3)
// vmcnt ladder (per-wave, 2 loads/phase, in-order retirement):
//   p1: vmcnt(4) -> forces prev tile's p3 stages (A1,A3 of CURRENT buf) landed
//       before this tile's p2-p3 reads; allows this tile's p0+p1 stages in flight.
//   p3: vmcnt(2) -> forces this tile's p0-p2 stages (B*,A0,A2 of NEXT buf) landed
//       before next tile's p0 reads; allows p3's pair in flight.
//   last tile (no staging): vmcnt(0) at p1/p3.
// WAR: stages at tile kt target buf[(kt+1)&1]; reads of buf[kt&1] were all SAMPLED
// (ds ops execute at LDS in issue order, consumed via lgkm(0) pre-MFMA) before
// kt's trailing barriers; kt+1's stages to buf[kt&1]... stages at kt+1 target
// buf[kt&1] only after kt+1's phases, i.e. after kt.p3's trailing barrier -> safe.
// Swizzle (128B rows, 8 x 16B chunks): stored chunk = logical ^ (row&7); since
// fragment rows have (row&7)==(l&7), read chunk = (kk*4 + (l>>4)) ^ (l&7): 16-lane
// groups cover all 8 chunks twice -> 2-way (free). Stage source pre-swizzled,
// LDS dest linear (rule #21).
template <int EPI, int NT, int GB>
__global__ __launch_bounds__(512, 2) void gemm256(
    const ushort* __restrict__ A, const ushort* __restrict__ Bt,
    const float* __restrict__ bias, const ushort* __restrict__ res16,
    ushort* __restrict__ out16, int M, int N, int K, int nb1) {
    extern __shared__ char smem[];  // 2 * 65536
    const int t = threadIdx.x;
    const int w = t >> 6, l = t & 63;
    const int wr = w >> 2, wc = w & 3;
    const int nwg = gridDim.x, cpx = nwg >> 3;
    const int swz = (blockIdx.x & 7) * cpx + (blockIdx.x >> 3);
    int bx0, by0;
    if (GB == 0) { bx0 = (swz % nb1) * NT; by0 = swz / nb1; }
    else         { bx0 = swz % nb1;        by0 = (swz / nb1) * NT; }

    // staging source base: storage row = t>>3, chunk = t&7, pre-swizzled k-chunk
    const int scoff = ((t & 7) ^ ((t >> 3) & 7)) * 8;
    const ushort* pA = A + (size_t)(by0 * 256 + (t >> 3)) * K + scoff;
    const ushort* pB = Bt + (size_t)(bx0 * 256 + (t >> 3)) * K + scoff;
    const size_t u64K = (size_t)64 * K;

    const int Kt = K >> 6;  // BK=64
    const int TOT = NT * Kt;
    int skt = 0;
    size_t adv = 0;  // B advance (GB=0) or A advance (GB=1) per stage tile

    // per-thread ds_read offsets; (frag-row & 7) == (l & 7) for all m/n
    const int cA0 = ((l >> 4) ^ (l & 7)) * 16;        // kk=0 chunk
    const int cA1 = ((4 + (l >> 4)) ^ (l & 7)) * 16;  // kk=1 chunk
    const int baseA = (wr * 128 + (l & 15)) * 128;
    const int baseB = 32768 + (wc * 64 + (l & 15)) * 128;

    char* nb = smem;  // prologue stage target = buf0

#define STG(uid)                                                                        \
    {                                                                                   \
        char* dst = nb + ((uid) < 4 ? (uid) * 8192 : 32768 + ((uid) - 4) * 8192) + (w << 10); \
        const ushort* s = ((uid) < 4)                                                   \
            ? (pA + (size_t)(uid) * u64K + (GB ? adv : 0) + skt * 64)                   \
            : (pB + (size_t)((uid) - 4) * u64K + (GB ? 0 : adv) + skt * 64);            \
        gload16(s, dst);                                                                \
    }

    // prologue: stage buf0 fully, consumption order
    STG(4); STG(5); STG(6); STG(7); STG(0); STG(2); STG(1); STG(3);
    if (++skt == Kt) { skt = 0; adv += (size_t)256 * K; }
    asm volatile("s_waitcnt vmcnt(2)" ::: "memory");
    __builtin_amdgcn_s_barrier();

    f32x4 acc[8][4] = {};
    bf16x8 b[4][2];
    int g = 0;
    for (int j = 0; j < NT; ++j) {
#pragma unroll 1
        for (int kt = 0; kt < Kt; ++kt, ++g) {
            const char* cb = smem + (g & 1) * 65536;
            nb = smem + ((g + 1) & 1) * 65536;
            const bool ds = (g + 1 < TOT);
#pragma unroll
            for (int p = 0; p < 4; ++p) {
                bf16x8 af[2][2];
                if (p == 0) {
#pragma unroll
                    for (int n = 0; n < 4; n++) {
                        b[n][0] = *(const bf16x8*)(cb + baseB + n * 2048 + cA0);
                        b[n][1] = *(const bf16x8*)(cb + baseB + n * 2048 + cA1);
                    }
                }
                af[0][0] = *(const bf16x8*)(cb + baseA + (2 * p) * 2048 + cA0);
                af[0][1] = *(const bf16x8*)(cb + baseA + (2 * p) * 2048 + cA1);
                af[1][0] = *(const bf16x8*)(cb + baseA + (2 * p + 1) * 2048 + cA0);
                af[1][1] = *(const bf16x8*)(cb + baseA + (2 * p + 1) * 2048 + cA1);
                if (ds) {
                    if (p == 0)      { STG(4); STG(5); }
                    else if (p == 1) { STG(6); STG(7); }
                    else if (p == 2) { STG(0); STG(2); }
                    else             { STG(1); STG(3); }
                }
                if (p == 0) asm volatile("s_waitcnt lgkmcnt(8)" ::: "memory");
                if (p == 1) {
                    if (ds) asm volatile("s_waitcnt vmcnt(4)" ::: "memory");
                    else    asm volatile("s_waitcnt vmcnt(0)" ::: "memory");
                }
                if (p == 3) {
                    if (ds) asm volatile("s_waitcnt vmcnt(2)" ::: "memory");
                    else    asm volatile("s_waitcnt vmcnt(0)" ::: "memory");
                }
                __builtin_amdgcn_sched_barrier(0);
                __builtin_amdgcn_s_barrier();
                asm volatile("s_waitcnt lgkmcnt(0)" ::: "memory");
                __builtin_amdgcn_sched_barrier(0);
                __builtin_amdgcn_s_setprio(1);
#pragma unroll
                for (int i = 0; i < 2; i++)
#pragma unroll
                    for (int n = 0; n < 4; n++) {
                        acc[2 * p + i][n] = __builtin_amdgcn_mfma_f32_16x16x32_bf16(
                            af[i][0], b[n][0], acc[2 * p + i][n], 0, 0, 0);
                        acc[2 * p + i][n] = __builtin_amdgcn_mfma_f32_16x16x32_bf16(
                            af[i][1], b[n][1], acc[2 * p + i][n], 0, 0, 0);
                    }
                __builtin_amdgcn_s_setprio(0);
                __builtin_amdgcn_sched_barrier(0);
                __builtin_amdgcn_s_barrier();
                __builtin_amdgcn_sched_barrier(0);
            }
            if (ds) {
                if (++skt == Kt) { skt = 0; adv += (size_t)256 * K; }
            }
        }

        // epilogue tile j (n innermost for full-sector store merge)
        {
            const int bx = (GB == 0) ? (bx0 + j) : bx0;
            const int by = (GB == 0) ? by0 : (by0 + j);
            const int row0 = by * 256 + wr * 128 + ((l >> 4) << 2);
            const int col0 = bx * 256 + wc * 64 + (l & 15);
            const int seg = bx >> 1;
            const size_t segoff = (size_t)seg * M * 512;
            const int c511 = col0 & 511;
            float bv[4];
#pragma unroll
            for (int n = 0; n < 4; n++) bv[n] = bias[col0 + n * 16];
#pragma unroll
            for (int m = 0; m < 8; m++) {
#pragma unroll
                for (int r = 0; r < 4; r++) {
                    const int row = row0 + m * 16 + r;
                    const size_t base = (size_t)row * N + col0;
#pragma unroll
                    for (int n = 0; n < 4; n++) {
                        float vv = acc[m][n][r] + bv[n];
                        if constexpr (EPI == 2) {
                            vv = vv > 0.f ? vv : 0.f;
                            out16[base + n * 16] = f2bf(vv);
                        } else if constexpr (EPI == 3) {
                            vv += bf2f(res16[base + n * 16]);
                            out16[base + n * 16] = f2bf(vv);
                        } else if constexpr (EPI == 4) {
                            if (seg < 2) vv = vv > 0.f ? vv + 1.f : __expf(vv);
                            out16[segoff + (size_t)row * 512 + c511 + n * 16] = f2bf(vv);
                        } else {
                            out16[base + n * 16] = f2bf(vv);
                        }
                    }
                }
            }
            if (j + 1 < NT) {
#pragma unroll
                for (int m = 0; m < 8; m++)
#pragma unroll
                    for (int n = 0; n < 4; n++)
                        acc[m][n] = (f32x4){0.f, 0.f, 0.f, 0.f};
            }
        }
    }
#undef STG
}

// ---------------- kv partial reduction ----------------
__global__ __launch_bounds__(256) void kv_partial(
    const ushort* __restrict__ km, const ushort* __restrict__ v,
    float* __restrict__ kvp, float* __restrict__ ksump, int S) {
    __shared__ ushort kms[32 * 64];
    __shared__ ushort vs[32 * 64];
    const int t = threadIdx.x;
    const int bh = blockIdx.y, b = bh >> 3, h = bh & 7;
    const int d0 = (t >> 4) * 4, e0 = (t & 15) * 4;
    float acc[4][4] = {};
    float ks = 0.f;
    const int s_base = blockIdx.x * 512;
    const int r = t >> 3, c8 = (t & 7) * 8;
    for (int s0 = 0; s0 < 512; s0 += 32) {
        size_t grow = ((size_t)b * S + s_base + s0 + r) * 512 + h * 64 + c8;
        *(uint4*)&kms[r * 64 + c8] = *(const uint4*)&km[grow];
        *(uint4*)&vs[r * 64 + c8] = *(const uint4*)&v[grow];
        __syncthreads();
#pragma unroll 4
        for (int s = 0; s < 32; ++s) {
            ushort4 ka = *(const ushort4*)&kms[s * 64 + d0];
            ushort4 vb = *(const ushort4*)&vs[s * 64 + e0];
            float a0 = bf2f(ka.x), a1 = bf2f(ka.y), a2 = bf2f(ka.z), a3 = bf2f(ka.w);
            float b0 = bf2f(vb.x), b1 = bf2f(vb.y), b2 = bf2f(vb.z), b3 = bf2f(vb.w);
            acc[0][0] += a0 * b0; acc[0][1] += a0 * b1; acc[0][2] += a0 * b2; acc[0][3] += a0 * b3;
            acc[1][0] += a1 * b0; acc[1][1] += a1 * b1; acc[1][2] += a1 * b2; acc[1][3] += a1 * b3;
            acc[2][0] += a2 * b0; acc[2][1] += a2 * b1; acc[2][2] += a2 * b2; acc[2][3] += a2 * b3;
            acc[3][0] += a3 * b0; acc[3][1] += a3 * b1; acc[3][2] += a3 * b2; acc[3][3] += a3 * b3;
            if (t < 64) ks += bf2f(kms[s * 64 + t]);
        }
        __syncthreads();
    }
    float* dst = kvp + ((size_t)bh * 16 + blockIdx.x) * 4096;
#pragma unroll
    for (int i = 0; i < 4; i++)
#pragma unroll
        for (int j = 0; j < 4; j++)
            dst[(d0 + i) * 64 + e0 + j] = acc[i][j];
    if (t < 64) ksump[((size_t)bh * 16 + blockIdx.x) * 64 + t] = ks;
}

// reduce partials; kv emitted TRANSPOSED per head as bf16: kvt[bh][e][d]
__global__ void kv_reduce(const float* __restrict__ kvp, const float* __restrict__ ksump,
                          ushort* __restrict__ kvt, float* __restrict__ ksum) {
    int i = blockIdx.x * 256 + threadIdx.x;
    if (i < 32 * 4096) {
        int bh = i >> 12, de = i & 4095;
        int d = de >> 6, e = de & 63;
        float s = 0.f;
#pragma unroll
        for (int c = 0; c < 16; ++c) s += kvp[((size_t)bh * 16 + c) * 4096 + de];
        kvt[(size_t)bh * 4096 + e * 64 + d] = f2bf(s);
    } else {
        int j = i - 32 * 4096;
        if (j < 32 * 64) {
            int bh = j >> 6, d = j & 63;
            float s = 0.f;
#pragma unroll
            for (int c = 0; c < 16; ++c) s += ksump[((size_t)bh * 16 + c) * 64 + d];
            ksum[j] = s;
        }
    }
}

// ---------------- attn via MFMA: per (b,h) attn = qm[S,64] @ kv[64,64], * z ----------------
__global__ __launch_bounds__(256) void attn_mfma(
    const ushort* __restrict__ qm, const ushort* __restrict__ kvt,
    const float* __restrict__ ksum, ushort* __restrict__ attnE, int S) {
    __shared__ ushort As[128 * 128];
    __shared__ ushort Bs[128 * 64];
    __shared__ float zbuf[128][2];
    __shared__ float ks2[128];
    const int t = threadIdx.x, w = t >> 6, l = t & 63;
    const int cx = blockIdx.x, by = blockIdx.y;
    const int b = (by * 128) / S;
    const int h0 = cx * 2;
    const size_t arow0 = (size_t)(by * 128) * 512 + cx * 128;

#pragma unroll
    for (int rd = 0; rd < 8; ++rd) {
        const ushort* g = qm + arow0 + (size_t)(rd * 16 + w * 4 + (l >> 4)) * 512 + (l & 15) * 8;
        gload16(g, (char*)As + rd * 4096 + w * 1024);
    }
    const ushort* kvbase = kvt + (size_t)(b * 8 + h0) * 4096;
#pragma unroll
    for (int rd = 0; rd < 4; ++rd) {
        const ushort* g = kvbase + (rd * 32 + w * 8 + (l >> 3)) * 64 + (l & 7) * 8;
        gload16(g, (char*)Bs + rd * 4096 + w * 1024);
    }
    if (t < 128) ks2[t] = ksum[(b * 8 + h0) * 64 + t];
    __syncthreads();

    {
        const int r = t >> 1, hh = t & 1;
        float den = 0.f;
#pragma unroll
        for (int d0 = 0; d0 < 64; d0 += 8) {
            bf16x8 qv = *(const bf16x8*)&As[r * 128 + hh * 64 + d0];
#pragma unroll
            for (int j = 0; j < 8; j++) den += bf2f((ushort)qv[j]) * ks2[hh * 64 + d0 + j];
        }
        zbuf[r][hh] = 1.0f / (den + 1e-6f);
    }

    const int wr = w >> 1, wc = w & 1;
    const int ar = wr * 64 + (l & 15);
    const int br = wc * 64 + (l & 15);
    const int ko = (l >> 4) * 8;
    f32x4 acc[4][4] = {};
#pragma unroll
    for (int ks_ = 0; ks_ < 2; ++ks_) {
        bf16x8 a[4], bb[4];
#pragma unroll
        for (int m = 0; m < 4; m++)
            a[m] = *(const bf16x8*)&As[(ar + m * 16) * 128 + wc * 64 + ks_ * 32 + ko];
#pragma unroll
        for (int n = 0; n < 4; n++)
            bb[n] = *(const bf16x8*)&Bs[(br + n * 16) * 64 + ks_ * 32 + ko];
#pragma unroll
        for (int m = 0; m < 4; m++)
#pragma unroll
            for (int n = 0; n < 4; n++)
                acc[m][n] = __builtin_amdgcn_mfma_f32_16x16x32_bf16(a[m], bb[n], acc[m][n], 0, 0, 0);
    }
    __syncthreads();

    const int row0l = wr * 64 + ((l >> 4) << 2);
    ushort* outbase = attnE + (size_t)(by * 128) * 512 + cx * 128;
#pragma unroll
    for (int n = 0; n < 4; n++) {
#pragma unroll
        for (int m = 0; m < 4; m++) {
#pragma unroll
            for (int r = 0; r < 4; r++) {
                int rl = row0l + m * 16 + r;
                float z = zbuf[rl][wc];
                outbase[(size_t)rl * 512 + wc * 64 + n * 16 + (l & 15)] = f2bf(acc[m][n][r] * z);
            }
        }
    }
}

// ---------------- LayerNorm over bf16 input ----------------
template <int OUT32>
__global__ __launch_bounds__(256) void ln_bf16(
    const ushort* __restrict__ in, const float* __restrict__ g, const float* __restrict__ be,
    void* __restrict__ outp, int Mrows) {
    const int w = threadIdx.x >> 6, l = threadIdx.x & 63;
    const int row = blockIdx.x * 4 + w;
    if (row >= Mrows) return;
    const ushort* rp = in + (size_t)row * 512;
    uint4 u = *(const uint4*)&rp[l * 8];
    float x[8];
    x[0] = bf2f((ushort)(u.x & 0xffff)); x[1] = bf2f((ushort)(u.x >> 16));
    x[2] = bf2f((ushort)(u.y & 0xffff)); x[3] = bf2f((ushort)(u.y >> 16));
    x[4] = bf2f((ushort)(u.z & 0xffff)); x[5] = bf2f((ushort)(u.z >> 16));
    x[6] = bf2f((ushort)(u.w & 0xffff)); x[7] = bf2f((ushort)(u.w >> 16));
    float s = 0.f, ss = 0.f;
#pragma unroll
    for (int j = 0; j < 8; j++) { s += x[j]; ss += x[j] * x[j]; }
#pragma unroll
    for (int o = 1; o < 64; o <<= 1) {
        s += __shfl_xor(s, o, 64);
        ss += __shfl_xor(ss, o, 64);
    }
    float mean = s * (1.f / 512.f);
    float var = ss * (1.f / 512.f) - mean * mean;
    float rstd = rsqrtf(var + 1e-5f);
    float4 g0 = *(const float4*)&g[l * 8], g1v = *(const float4*)&g[l * 8 + 4];
    float4 b0 = *(const float4*)&be[l * 8], b1v = *(const float4*)&be[l * 8 + 4];
    float o0[8];
    o0[0] = (x[0] - mean) * rstd * g0.x + b0.x;
    o0[1] = (x[1] - mean) * rstd * g0.y + b0.y;
    o0[2] = (x[2] - mean) * rstd * g0.z + b0.z;
    o0[3] = (x[3] - mean) * rstd * g0.w + b0.w;
    o0[4] = (x[4] - mean) * rstd * g1v.x + b1v.x;
    o0[5] = (x[5] - mean) * rstd * g1v.y + b1v.y;
    o0[6] = (x[6] - mean) * rstd * g1v.z + b1v.z;
    o0[7] = (x[7] - mean) * rstd * g1v.w + b1v.w;
    if constexpr (OUT32) {
        float* op = (float*)outp + (size_t)row * 512;
        *(float4*)&op[l * 8] = make_float4(o0[0], o0[1], o0[2], o0[3]);
        *(float4*)&op[l * 8 + 4] = make_float4(o0[4], o0[5], o0[6], o0[7]);
    } else {
        ushort* op = (ushort*)outp + (size_t)row * 512;
        ushort4 u0, u1;
        u0.x = f2bf(o0[0]); u0.y = f2bf(o0[1]); u0.z = f2bf(o0[2]); u0.w = f2bf(o0[3]);
        u1.x = f2bf(o0[4]); u1.y = f2bf(o0[5]); u1.z = f2bf(o0[6]); u1.w = f2bf(o0[7]);
        *(ushort4*)&op[l * 8] = u0;
        *(ushort4*)&op[l * 8 + 4] = u1;
    }
}

extern "C" void kernel_launch(void* const* d_in, const int* in_sizes, int n_in,
                              void* d_out, int out_size, void* d_ws, size_t ws_size,
                              hipStream_t stream) {
    const int B = 4, S = 8192, E = 512, F = 2048;
    const int M = B * S;  // 32768
    const size_t SZ = (size_t)M * E * 2;  // 32 MiB
    const int SMEM = 131072;

    const float* src = (const float*)d_in[0];
    const float* Wq = (const float*)d_in[1];  const float* bq = (const float*)d_in[2];
    const float* Wk = (const float*)d_in[3];  const float* bk = (const float*)d_in[4];
    const float* Wv = (const float*)d_in[5];  const float* bv = (const float*)d_in[6];
    const float* Wo = (const float*)d_in[7];  const float* bo = (const float*)d_in[8];
    const float* W1 = (const float*)d_in[9];  const float* b1 = (const float*)d_in[10];
    const float* W2 = (const float*)d_in[11]; const float* b2 = (const float*)d_in[12];
    const float* g1 = (const float*)d_in[13]; const float* be1 = (const float*)d_in[14];
    const float* g2 = (const float*)d_in[15]; const float* be2 = (const float*)d_in[16];

    char* ws = (char*)d_ws;
    ushort* qm    = (ushort*)(ws + 0 * SZ);
    ushort* km    = (ushort*)(ws + 1 * SZ);
    ushort* v     = (ushort*)(ws + 2 * SZ);
    ushort* src16 = (ushort*)(ws + 3 * SZ);
    ushort* x16   = (ushort*)(ws + 4 * SZ);
    ushort* z16   = (ushort*)(ws + 5 * SZ);
    char*   tail  = ws + 6 * SZ;
    float*  kvp   = (float*)(tail);
    float*  ksump = (float*)(tail + 8388608);
    ushort* kvt   = (ushort*)(tail + 8519680);
    float*  ksum  = (float*)(tail + 8781824);
    float*  bqkv  = (float*)(tail + 8790016);
    ushort* wqkv  = (ushort*)(tail + 8796160);
    ushort* wot   = (ushort*)(tail + 10369024);
    ushort* w1t   = (ushort*)(tail + 10893312);
    ushort* w2t   = (ushort*)(tail + 12990464);
    ushort* attnE = km;
    ushort* y16   = v;
    ushort* hbuf  = (ushort*)(ws + 0);

    hipFuncSetAttribute((const void*)gemm256<4, 3, 0>, hipFuncAttributeMaxDynamicSharedMemorySize, SMEM);
    hipFuncSetAttribute((const void*)gemm256<3, 1, 0>, hipFuncAttributeMaxDynamicSharedMemorySize, SMEM);
    hipFuncSetAttribute((const void*)gemm256<2, 4, 1>, hipFuncAttributeMaxDynamicSharedMemorySize, SMEM);

    // 1) merged prep
    prep<<<dim3(16384 + 3072 + 6), 256, 0, stream>>>(
        src, src16, Wq, Wk, Wv, Wo, W1, W2, wqkv, wot, w1t, w2t, bq, bk, bv, bqkv);

    // 2) fused QKV GEMM (N=1536, NT=3 over bx -> 256 blocks; elu+1 on q,k segments)
    gemm256<4, 3, 0><<<dim3(2 * 128), 512, SMEM, stream>>>(src16, wqkv, bqkv, nullptr, qm, M, 1536, E, 2);

    // 3) kv / ksum reduction
    kv_partial<<<dim3(16, 32), 256, 0, stream>>>(km, v, kvp, ksump, S);
    kv_reduce<<<dim3((32 * 4096 + 32 * 64 + 255) / 256), 256, 0, stream>>>(kvp, ksump, kvt, ksum);

    // 4) attention combine (MFMA)
    attn_mfma<<<dim3(4, M / 128), 256, 0, stream>>>(qm, kvt, ksum, attnE, S);

    // 5) output proj + bf16 residual, then LN -> x16
    gemm256<3, 1, 0><<<dim3(2 * 128), 512, SMEM, stream>>>(attnE, wot, bo, src16, y16, M, E, E, 2);
    ln_bf16<0><<<dim3(M / 4), 256, 0, stream>>>(y16, g1, be1, x16, M);

    // 6) FFN: W1 (NT=4 over by -> 256 blocks, A streamed once), W2 (Kt=32, NT=1)
    gemm256<2, 4, 1><<<dim3(8 * 32), 512, SMEM, stream>>>(x16, w1t, b1, nullptr, hbuf, M, F, E, 8);
    gemm256<3, 1, 0><<<dim3(2 * 128), 512, SMEM, stream>>>(hbuf, w2t, b2, x16, z16, M, E, F, 2);
    ln_bf16<1><<<dim3(M / 4), 256, 0, stream>>>(z16, g2, be2, (float*)d_out, M);
}

// Round 12
// 357.474 us; speedup vs baseline: 1.0528x; 1.0528x over previous
//
#include <hip/hip_runtime.h>
#include <hip/hip_bf16.h>

typedef __attribute__((ext_vector_type(8))) short bf16x8;
typedef __attribute__((ext_vector_type(4))) float f32x4;

__device__ inline ushort f2bf(float f) {
    uint u = __float_as_uint(f);
    u += 0x7fff + ((u >> 16) & 1);
    return (ushort)(u >> 16);
}
__device__ inline float bf2f(ushort h) {
    return __uint_as_float(((uint)h) << 16);
}

__device__ inline void gload16(const void* g, void* lds) {
    __builtin_amdgcn_global_load_lds(
        (const __attribute__((address_space(1))) void*)g,
        (__attribute__((address_space(3))) void*)lds, 16, 0, 0);
}

// ---------------- merged prep: src->bf16, 6 weight transpose-converts, bias concat ----------------
__global__ __launch_bounds__(256) void prep(
    const float* __restrict__ src, ushort* __restrict__ src16,
    const float* __restrict__ Wq, const float* __restrict__ Wk,
    const float* __restrict__ Wv, const float* __restrict__ Wo,
    const float* __restrict__ W1, const float* __restrict__ W2,
    ushort* __restrict__ wqkv, ushort* __restrict__ wot,
    ushort* __restrict__ w1t, ushort* __restrict__ w2t,
    const float* __restrict__ bq, const float* __restrict__ bk,
    const float* __restrict__ bv, float* __restrict__ bqkv) {
    __shared__ float tile[32][33];
    int bid = blockIdx.x;
    const int t = threadIdx.x;
    if (bid < 16384) {
        int i = bid * 256 + t;
        float4 a = ((const float4*)src)[i];
        ushort4 o;
        o.x = f2bf(a.x); o.y = f2bf(a.y); o.z = f2bf(a.z); o.w = f2bf(a.w);
        ((ushort4*)src16)[i] = o;
        return;
    }
    bid -= 16384;
    const float* in; ushort* out; int Kd, Nd;
    if (bid < 1024) {
        int m = bid >> 8;
        in = (m == 0) ? Wq : (m == 1) ? Wk : (m == 2) ? Wv : Wo;
        out = (m == 3) ? wot : (wqkv + m * 512 * 512);
        Kd = 512; Nd = 512; bid &= 255;
    } else if (bid < 2048) { in = W1; out = w1t; Kd = 512; Nd = 2048; bid -= 1024; }
    else if (bid < 3072) { in = W2; out = w2t; Kd = 2048; Nd = 512; bid -= 2048; }
    else {
        int i = (bid - 3072) * 256 + t;
        if (i < 512) bqkv[i] = bq[i];
        else if (i < 1024) bqkv[i] = bk[i - 512];
        else if (i < 1536) bqkv[i] = bv[i - 1024];
        return;
    }
    const int nx = Nd / 32;
    const int nbase = (bid % nx) * 32, kb = (bid / nx) * 32;
    const int tx = t & 31, ty = t >> 5;
#pragma unroll
    for (int i = 0; i < 4; i++)
        tile[ty + i * 8][tx] = in[(size_t)(kb + ty + i * 8) * Nd + nbase + tx];
    __syncthreads();
#pragma unroll
    for (int i = 0; i < 4; i++) {
        int n = nbase + ty + i * 8, k = kb + tx;
        out[(size_t)n * Kd + k] = f2bf(tile[tx][ty + i * 8]);
    }
}

// ============ 256x256 persistent GEMM: BK=64, 2x64KB dbuf, ONE barrier per K-tile ============
// (512,2), 8 waves 2Mx4N. Region g (one BK=64 K-tile):
//   [vmcnt(0) -- EXACT: only stage(g)'s 8 loads outstanding]  [s_barrier]
//   [sched_barrier(0): reads must not hoist above]
//   [stage(g+1): 8 gload16 units -> buf[(g+1)&1]]
//   [kk0 reads (12 ds_read_b128) ; 32 MFMA ; kk1 reads ; 32 MFMA]  -- single
//   scheduling window: backend interleaves with counted lgkmcnt, may hoist kk1
//   reads under kk0 MFMAs. No setprio, no trailing fences (T5 null for lockstep).
// WAR: stage(g+1) writes buf[(g+1)&1] == buf[(g-1)&1]; all waves consumed their
// buf[g-1] reads inside region g-1 (auto-lgkm before MFMA use) and then passed
// region g's barrier before stage(g+1) issues -> no overwrite race.
// vmcnt(0) at top of g waits only stage(g) (issued one full region ago, ~4000 cyc
// vs ~1200 cyc L2 service -> normally already landed). Epilogue stores (NT
// boundaries) add a one-off conservative drain -- negligible.
// Swizzle (128B rows, 8x16B chunks, r11-proven): stored chunk = logical ^ (row&7);
// frag rows have (row&7)==(l&7) -> read chunk (kk*4 + (l>>4)) ^ (l&7). Stage source
// pre-swizzled, LDS dest linear (rule #21).
// GB=0: persist over bx; GB=1: persist over by.
// EPI: 2 = relu bf16; 3 = bf16 residual add; 4 = fused QKV (seg<2: elu+1) -> [3][M][512]
template <int EPI, int NT, int GB>
__global__ __launch_bounds__(512, 2) void gemm256(
    const ushort* __restrict__ A, const ushort* __restrict__ Bt,
    const float* __restrict__ bias, const ushort* __restrict__ res16,
    ushort* __restrict__ out16, int M, int N, int K, int nb1) {
    extern __shared__ char smem[];  // 2 * 65536
    const int t = threadIdx.x;
    const int w = t >> 6, l = t & 63;
    const int wr = w >> 2, wc = w & 3;
    const int nwg = gridDim.x, cpx = nwg >> 3;
    const int swz = (blockIdx.x & 7) * cpx + (blockIdx.x >> 3);
    int bx0, by0;
    if (GB == 0) { bx0 = (swz % nb1) * NT; by0 = swz / nb1; }
    else         { bx0 = swz % nb1;        by0 = (swz / nb1) * NT; }

    // staging source: storage row = t>>3 (one 64-row unit per STG), chunk = t&7,
    // source logical chunk pre-swizzled by (row&7)
    const int scoff = ((t & 7) ^ ((t >> 3) & 7)) * 8;
    const ushort* pA = A + (size_t)(by0 * 256 + (t >> 3)) * K + scoff;
    const ushort* pB = Bt + (size_t)(bx0 * 256 + (t >> 3)) * K + scoff;
    const size_t u64K = (size_t)64 * K;

    const int Kt = K >> 6;  // BK=64
    const int TOT = NT * Kt;
    int skt = 0;
    size_t adv = 0;  // per-tile-group advance: B (GB=0) or A (GB=1)

#define STG8(buf)                                                              \
    {                                                                          \
        char* Lb = (buf) + (w << 10);                                          \
        _Pragma("unroll")                                                      \
        for (int u = 0; u < 4; ++u) {                                          \
            gload16(pA + (size_t)u * u64K + (GB ? adv : 0) + skt * 64,         \
                    Lb + u * 8192);                                            \
            gload16(pB + (size_t)u * u64K + (GB ? 0 : adv) + skt * 64,         \
                    Lb + 32768 + u * 8192);                                    \
        }                                                                      \
        if (++skt == Kt) { skt = 0; adv += (size_t)256 * K; }                  \
    }

    // per-thread ds_read offsets; (frag-row & 7) == (l & 7) for all m/n
    const int cA0 = ((l >> 4) ^ (l & 7)) * 16;        // kk=0 stored chunk
    const int cA1 = ((4 + (l >> 4)) ^ (l & 7)) * 16;  // kk=1 stored chunk
    const int baseA = (wr * 128 + (l & 15)) * 128;
    const int baseB = 32768 + (wc * 64 + (l & 15)) * 128;

    // prologue: stage tile 0 into buf0
    STG8(smem);

    f32x4 acc[8][4] = {};
    int g = 0;
    for (int j = 0; j < NT; ++j) {
#pragma unroll 1
        for (int kt = 0; kt < Kt; ++kt, ++g) {
            asm volatile("s_waitcnt vmcnt(0)" ::: "memory");  // stage(g) landed (exact)
            __builtin_amdgcn_s_barrier();                     // visible to all waves
            __builtin_amdgcn_sched_barrier(0);                // no reads above barrier

            const char* cb = smem + (g & 1) * 65536;
            if (g + 1 < TOT) STG8(smem + ((g + 1) & 1) * 65536);

            bf16x8 a[8], b[4];
            // kk0
#pragma unroll
            for (int n = 0; n < 4; n++) b[n] = *(const bf16x8*)(cb + baseB + n * 2048 + cA0);
#pragma unroll
            for (int m = 0; m < 8; m++) a[m] = *(const bf16x8*)(cb + baseA + m * 2048 + cA0);
#pragma unroll
            for (int m = 0; m < 8; m++)
#pragma unroll
                for (int n = 0; n < 4; n++)
                    acc[m][n] = __builtin_amdgcn_mfma_f32_16x16x32_bf16(a[m], b[n], acc[m][n], 0, 0, 0);
            // kk1
#pragma unroll
            for (int n = 0; n < 4; n++) b[n] = *(const bf16x8*)(cb + baseB + n * 2048 + cA1);
#pragma unroll
            for (int m = 0; m < 8; m++) a[m] = *(const bf16x8*)(cb + baseA + m * 2048 + cA1);
#pragma unroll
            for (int m = 0; m < 8; m++)
#pragma unroll
                for (int n = 0; n < 4; n++)
                    acc[m][n] = __builtin_amdgcn_mfma_f32_16x16x32_bf16(a[m], b[n], acc[m][n], 0, 0, 0);
        }

        // epilogue tile j (no LDS; n innermost for full-sector store merge)
        {
            const int bx = (GB == 0) ? (bx0 + j) : bx0;
            const int by = (GB == 0) ? by0 : (by0 + j);
            const int row0 = by * 256 + wr * 128 + ((l >> 4) << 2);
            const int col0 = bx * 256 + wc * 64 + (l & 15);
            const int seg = bx >> 1;
            const size_t segoff = (size_t)seg * M * 512;
            const int c511 = col0 & 511;
            float bv[4];
#pragma unroll
            for (int n = 0; n < 4; n++) bv[n] = bias[col0 + n * 16];
#pragma unroll
            for (int m = 0; m < 8; m++) {
#pragma unroll
                for (int r = 0; r < 4; r++) {
                    const int row = row0 + m * 16 + r;
                    const size_t base = (size_t)row * N + col0;
#pragma unroll
                    for (int n = 0; n < 4; n++) {
                        float vv = acc[m][n][r] + bv[n];
                        if constexpr (EPI == 2) {
                            vv = vv > 0.f ? vv : 0.f;
                            out16[base + n * 16] = f2bf(vv);
                        } else if constexpr (EPI == 3) {
                            vv += bf2f(res16[base + n * 16]);
                            out16[base + n * 16] = f2bf(vv);
                        } else if constexpr (EPI == 4) {
                            if (seg < 2) vv = vv > 0.f ? vv + 1.f : __expf(vv);
                            out16[segoff + (size_t)row * 512 + c511 + n * 16] = f2bf(vv);
                        } else {
                            out16[base + n * 16] = f2bf(vv);
                        }
                    }
                }
            }
            if (j + 1 < NT) {
#pragma unroll
                for (int m = 0; m < 8; m++)
#pragma unroll
                    for (int n = 0; n < 4; n++)
                        acc[m][n] = (f32x4){0.f, 0.f, 0.f, 0.f};
            }
        }
    }
#undef STG8
}

// ---------------- kv partial reduction ----------------
__global__ __launch_bounds__(256) void kv_partial(
    const ushort* __restrict__ km, const ushort* __restrict__ v,
    float* __restrict__ kvp, float* __restrict__ ksump, int S) {
    __shared__ ushort kms[32 * 64];
    __shared__ ushort vs[32 * 64];
    const int t = threadIdx.x;
    const int bh = blockIdx.y, b = bh >> 3, h = bh & 7;
    const int d0 = (t >> 4) * 4, e0 = (t & 15) * 4;
    float acc[4][4] = {};
    float ks = 0.f;
    const int s_base = blockIdx.x * 512;
    const int r = t >> 3, c8 = (t & 7) * 8;
    for (int s0 = 0; s0 < 512; s0 += 32) {
        size_t grow = ((size_t)b * S + s_base + s0 + r) * 512 + h * 64 + c8;
        *(uint4*)&kms[r * 64 + c8] = *(const uint4*)&km[grow];
        *(uint4*)&vs[r * 64 + c8] = *(const uint4*)&v[grow];
        __syncthreads();
#pragma unroll 4
        for (int s = 0; s < 32; ++s) {
            ushort4 ka = *(const ushort4*)&kms[s * 64 + d0];
            ushort4 vb = *(const ushort4*)&vs[s * 64 + e0];
            float a0 = bf2f(ka.x), a1 = bf2f(ka.y), a2 = bf2f(ka.z), a3 = bf2f(ka.w);
            float b0 = bf2f(vb.x), b1 = bf2f(vb.y), b2 = bf2f(vb.z), b3 = bf2f(vb.w);
            acc[0][0] += a0 * b0; acc[0][1] += a0 * b1; acc[0][2] += a0 * b2; acc[0][3] += a0 * b3;
            acc[1][0] += a1 * b0; acc[1][1] += a1 * b1; acc[1][2] += a1 * b2; acc[1][3] += a1 * b3;
            acc[2][0] += a2 * b0; acc[2][1] += a2 * b1; acc[2][2] += a2 * b2; acc[2][3] += a2 * b3;
            acc[3][0] += a3 * b0; acc[3][1] += a3 * b1; acc[3][2] += a3 * b2; acc[3][3] += a3 * b3;
            if (t < 64) ks += bf2f(kms[s * 64 + t]);
        }
        __syncthreads();
    }
    float* dst = kvp + ((size_t)bh * 16 + blockIdx.x) * 4096;
#pragma unroll
    for (int i = 0; i < 4; i++)
#pragma unroll
        for (int j = 0; j < 4; j++)
            dst[(d0 + i) * 64 + e0 + j] = acc[i][j];
    if (t < 64) ksump[((size_t)bh * 16 + blockIdx.x) * 64 + t] = ks;
}

// reduce partials; kv emitted TRANSPOSED per head as bf16: kvt[bh][e][d]
__global__ void kv_reduce(const float* __restrict__ kvp, const float* __restrict__ ksump,
                          ushort* __restrict__ kvt, float* __restrict__ ksum) {
    int i = blockIdx.x * 256 + threadIdx.x;
    if (i < 32 * 4096) {
        int bh = i >> 12, de = i & 4095;
        int d = de >> 6, e = de & 63;
        float s = 0.f;
#pragma unroll
        for (int c = 0; c < 16; ++c) s += kvp[((size_t)bh * 16 + c) * 4096 + de];
        kvt[(size_t)bh * 4096 + e * 64 + d] = f2bf(s);
    } else {
        int j = i - 32 * 4096;
        if (j < 32 * 64) {
            int bh = j >> 6, d = j & 63;
            float s = 0.f;
#pragma unroll
            for (int c = 0; c < 16; ++c) s += ksump[((size_t)bh * 16 + c) * 64 + d];
            ksum[j] = s;
        }
    }
}

// ---------------- attn via MFMA: per (b,h) attn = qm[S,64] @ kv[64,64], * z ----------------
__global__ __launch_bounds__(256) void attn_mfma(
    const ushort* __restrict__ qm, const ushort* __restrict__ kvt,
    const float* __restrict__ ksum, ushort* __restrict__ attnE, int S) {
    __shared__ ushort As[128 * 128];
    __shared__ ushort Bs[128 * 64];
    __shared__ float zbuf[128][2];
    __shared__ float ks2[128];
    const int t = threadIdx.x, w = t >> 6, l = t & 63;
    const int cx = blockIdx.x, by = blockIdx.y;
    const int b = (by * 128) / S;
    const int h0 = cx * 2;
    const size_t arow0 = (size_t)(by * 128) * 512 + cx * 128;

#pragma unroll
    for (int rd = 0; rd < 8; ++rd) {
        const ushort* g = qm + arow0 + (size_t)(rd * 16 + w * 4 + (l >> 4)) * 512 + (l & 15) * 8;
        gload16(g, (char*)As + rd * 4096 + w * 1024);
    }
    const ushort* kvbase = kvt + (size_t)(b * 8 + h0) * 4096;
#pragma unroll
    for (int rd = 0; rd < 4; ++rd) {
        const ushort* g = kvbase + (rd * 32 + w * 8 + (l >> 3)) * 64 + (l & 7) * 8;
        gload16(g, (char*)Bs + rd * 4096 + w * 1024);
    }
    if (t < 128) ks2[t] = ksum[(b * 8 + h0) * 64 + t];
    __syncthreads();

    {
        const int r = t >> 1, hh = t & 1;
        float den = 0.f;
#pragma unroll
        for (int d0 = 0; d0 < 64; d0 += 8) {
            bf16x8 qv = *(const bf16x8*)&As[r * 128 + hh * 64 + d0];
#pragma unroll
            for (int j = 0; j < 8; j++) den += bf2f((ushort)qv[j]) * ks2[hh * 64 + d0 + j];
        }
        zbuf[r][hh] = 1.0f / (den + 1e-6f);
    }

    const int wr = w >> 1, wc = w & 1;
    const int ar = wr * 64 + (l & 15);
    const int br = wc * 64 + (l & 15);
    const int ko = (l >> 4) * 8;
    f32x4 acc[4][4] = {};
#pragma unroll
    for (int ks_ = 0; ks_ < 2; ++ks_) {
        bf16x8 a[4], bb[4];
#pragma unroll
        for (int m = 0; m < 4; m++)
            a[m] = *(const bf16x8*)&As[(ar + m * 16) * 128 + wc * 64 + ks_ * 32 + ko];
#pragma unroll
        for (int n = 0; n < 4; n++)
            bb[n] = *(const bf16x8*)&Bs[(br + n * 16) * 64 + ks_ * 32 + ko];
#pragma unroll
        for (int m = 0; m < 4; m++)
#pragma unroll
            for (int n = 0; n < 4; n++)
                acc[m][n] = __builtin_amdgcn_mfma_f32_16x16x32_bf16(a[m], bb[n], acc[m][n], 0, 0, 0);
    }
    __syncthreads();

    const int row0l = wr * 64 + ((l >> 4) << 2);
    ushort* outbase = attnE + (size_t)(by * 128) * 512 + cx * 128;
#pragma unroll
    for (int n = 0; n < 4; n++) {
#pragma unroll
        for (int m = 0; m < 4; m++) {
#pragma unroll
            for (int r = 0; r < 4; r++) {
                int rl = row0l + m * 16 + r;
                float z = zbuf[rl][wc];
                outbase[(size_t)rl * 512 + wc * 64 + n * 16 + (l & 15)] = f2bf(acc[m][n][r] * z);
            }
        }
    }
}

// ---------------- LayerNorm over bf16 input ----------------
template <int OUT32>
__global__ __launch_bounds__(256) void ln_bf16(
    const ushort* __restrict__ in, const float* __restrict__ g, const float* __restrict__ be,
    void* __restrict__ outp, int Mrows) {
    const int w = threadIdx.x >> 6, l = threadIdx.x & 63;
    const int row = blockIdx.x * 4 + w;
    if (row >= Mrows) return;
    const ushort* rp = in + (size_t)row * 512;
    uint4 u = *(const uint4*)&rp[l * 8];
    float x[8];
    x[0] = bf2f((ushort)(u.x & 0xffff)); x[1] = bf2f((ushort)(u.x >> 16));
    x[2] = bf2f((ushort)(u.y & 0xffff)); x[3] = bf2f((ushort)(u.y >> 16));
    x[4] = bf2f((ushort)(u.z & 0xffff)); x[5] = bf2f((ushort)(u.z >> 16));
    x[6] = bf2f((ushort)(u.w & 0xffff)); x[7] = bf2f((ushort)(u.w >> 16));
    float s = 0.f, ss = 0.f;
#pragma unroll
    for (int j = 0; j < 8; j++) { s += x[j]; ss += x[j] * x[j]; }
#pragma unroll
    for (int o = 1; o < 64; o <<= 1) {
        s += __shfl_xor(s, o, 64);
        ss += __shfl_xor(ss, o, 64);
    }
    float mean = s * (1.f / 512.f);
    float var = ss * (1.f / 512.f) - mean * mean;
    float rstd = rsqrtf(var + 1e-5f);
    float4 g0 = *(const float4*)&g[l * 8], g1v = *(const float4*)&g[l * 8 + 4];
    float4 b0 = *(const float4*)&be[l * 8], b1v = *(const float4*)&be[l * 8 + 4];
    float o0[8];
    o0[0] = (x[0] - mean) * rstd * g0.x + b0.x;
    o0[1] = (x[1] - mean) * rstd * g0.y + b0.y;
    o0[2] = (x[2] - mean) * rstd * g0.z + b0.z;
    o0[3] = (x[3] - mean) * rstd * g0.w + b0.w;
    o0[4] = (x[4] - mean) * rstd * g1v.x + b1v.x;
    o0[5] = (x[5] - mean) * rstd * g1v.y + b1v.y;
    o0[6] = (x[6] - mean) * rstd * g1v.z + b1v.z;
    o0[7] = (x[7] - mean) * rstd * g1v.w + b1v.w;
    if constexpr (OUT32) {
        float* op = (float*)outp + (size_t)row * 512;
        *(float4*)&op[l * 8] = make_float4(o0[0], o0[1], o0[2], o0[3]);
        *(float4*)&op[l * 8 + 4] = make_float4(o0[4], o0[5], o0[6], o0[7]);
    } else {
        ushort* op = (ushort*)outp + (size_t)row * 512;
        ushort4 u0, u1;
        u0.x = f2bf(o0[0]); u0.y = f2bf(o0[1]); u0.z = f2bf(o0[2]); u0.w = f2bf(o0[3]);
        u1.x = f2bf(o0[4]); u1.y = f2bf(o0[5]); u1.z = f2bf(o0[6]); u1.w = f2bf(o0[7]);
        *(ushort4*)&op[l * 8] = u0;
        *(ushort4*)&op[l * 8 + 4] = u1;
    }
}

extern "C" void kernel_launch(void* const* d_in, const int* in_sizes, int n_in,
                              void* d_out, int out_size, void* d_ws, size_t ws_size,
                              hipStream_t stream) {
    const int B = 4, S = 8192, E = 512, F = 2048;
    const int M = B * S;  // 32768
    const size_t SZ = (size_t)M * E * 2;  // 32 MiB
    const int SMEM = 131072;

    const float* src = (const float*)d_in[0];
    const float* Wq = (const float*)d_in[1];  const float* bq = (const float*)d_in[2];
    const float* Wk = (const float*)d_in[3];  const float* bk = (const float*)d_in[4];
    const float* Wv = (const float*)d_in[5];  const float* bv = (const float*)d_in[6];
    const float* Wo = (const float*)d_in[7];  const float* bo = (const float*)d_in[8];
    const float* W1 = (const float*)d_in[9];  const float* b1 = (const float*)d_in[10];
    const float* W2 = (const float*)d_in[11]; const float* b2 = (const float*)d_in[12];
    const float* g1 = (const float*)d_in[13]; const float* be1 = (const float*)d_in[14];
    const float* g2 = (const float*)d_in[15]; const float* be2 = (const float*)d_in[16];

    char* ws = (char*)d_ws;
    ushort* qm    = (ushort*)(ws + 0 * SZ);
    ushort* km    = (ushort*)(ws + 1 * SZ);
    ushort* v     = (ushort*)(ws + 2 * SZ);
    ushort* src16 = (ushort*)(ws + 3 * SZ);
    ushort* x16   = (ushort*)(ws + 4 * SZ);
    ushort* z16   = (ushort*)(ws + 5 * SZ);
    char*   tail  = ws + 6 * SZ;
    float*  kvp   = (float*)(tail);
    float*  ksump = (float*)(tail + 8388608);
    ushort* kvt   = (ushort*)(tail + 8519680);
    float*  ksum  = (float*)(tail + 8781824);
    float*  bqkv  = (float*)(tail + 8790016);
    ushort* wqkv  = (ushort*)(tail + 8796160);
    ushort* wot   = (ushort*)(tail + 10369024);
    ushort* w1t   = (ushort*)(tail + 10893312);
    ushort* w2t   = (ushort*)(tail + 12990464);
    ushort* attnE = km;
    ushort* y16   = v;
    ushort* hbuf  = (ushort*)(ws + 0);

    hipFuncSetAttribute((const void*)gemm256<4, 3, 0>, hipFuncAttributeMaxDynamicSharedMemorySize, SMEM);
    hipFuncSetAttribute((const void*)gemm256<3, 1, 0>, hipFuncAttributeMaxDynamicSharedMemorySize, SMEM);
    hipFuncSetAttribute((const void*)gemm256<2, 4, 1>, hipFuncAttributeMaxDynamicSharedMemorySize, SMEM);

    // 1) merged prep
    prep<<<dim3(16384 + 3072 + 6), 256, 0, stream>>>(
        src, src16, Wq, Wk, Wv, Wo, W1, W2, wqkv, wot, w1t, w2t, bq, bk, bv, bqkv);

    // 2) fused QKV GEMM (N=1536, NT=3 over bx -> 256 blocks; elu+1 on q,k segments)
    gemm256<4, 3, 0><<<dim3(2 * 128), 512, SMEM, stream>>>(src16, wqkv, bqkv, nullptr, qm, M, 1536, E, 2);

    // 3) kv / ksum reduction
    kv_partial<<<dim3(16, 32), 256, 0, stream>>>(km, v, kvp, ksump, S);
    kv_reduce<<<dim3((32 * 4096 + 32 * 64 + 255) / 256), 256, 0, stream>>>(kvp, ksump, kvt, ksum);

    // 4) attention combine (MFMA)
    attn_mfma<<<dim3(4, M / 128), 256, 0, stream>>>(qm, kvt, ksum, attnE, S);

    // 5) output proj + bf16 residual, then LN -> x16
    gemm256<3, 1, 0><<<dim3(2 * 128), 512, SMEM, stream>>>(attnE, wot, bo, src16, y16, M, E, E, 2);
    ln_bf16<0><<<dim3(M / 4), 256, 0, stream>>>(y16, g1, be1, x16, M);

    // 6) FFN: W1 (NT=4 over by -> 256 blocks, A streamed once), W2 (Kt=32, NT=1)
    gemm256<2, 4, 1><<<dim3(8 * 32), 512, SMEM, stream>>>(x16, w1t, b1, nullptr, hbuf, M, F, E, 8);
    gemm256<3, 1, 0><<<dim3(2 * 128), 512, SMEM, stream>>>(hbuf, w2t, b2, x16, z16, M, E, F, 2);
    ln_bf16<1><<<dim3(M / 4), 256, 0, stream>>>(z16, g2, be2, (float*)d_out, M);
}